// Round 2
// baseline (1067.918 us; speedup 1.0000x reference)
//
#include <hip/hip_runtime.h>
#include <math.h>

#define EDIM 4096
#define BS 32
#define CPL 2                 // columns per lane (float2 weight loads)
#define COLS 128              // columns per block (64 lanes * CPL); all 4 waves share them
#define KWAVES 4              // internal k-split across the 4 waves of a block
#define BLK 256

__device__ __forceinline__ float relu_f(float x) { return x > 0.f ? x : 0.f; }

// ---------------------------------------------------------------------------
// prep: A0 = relu(BN(image)) stored feature-major [E][32]; v = relu(fs_bn_b[E:2E]);
// flag = any(v != 0)  (text half of BN(concat) is exactly fs_bn_b[E:] since the
// tiled text row is constant over the batch -> (x-mu)==0 -> text_features unused).
// ---------------------------------------------------------------------------
__global__ void __launch_bounds__(BLK) prep_kernel(
    const float* __restrict__ img, const float* __restrict__ bng,
    const float* __restrict__ bnb, float* __restrict__ act0,
    float* __restrict__ vvec, int* __restrict__ flag)
{
  int n = blockIdx.x * BLK + threadIdx.x;  // 0..EDIM-1
  float bv = bnb[EDIM + n];
  float vv = relu_f(bv);
  vvec[n] = vv;
  if (vv != 0.f) atomicOr(flag, 1);

  float s = 0.f, s2 = 0.f;
  for (int r = 0; r < BS; ++r) {
    float x = img[(size_t)r * EDIM + n];
    s += x; s2 += x * x;
  }
  float mean = s * (1.f / BS);
  float var  = s2 * (1.f / BS) - mean * mean;
  float sc = bng[n] * rsqrtf(var + 1e-5f);
  float sh = bnb[n] - mean * sc;
  for (int r = 0; r < BS; ++r) {
    float x = img[(size_t)r * EDIM + n];
    act0[(size_t)n * BS + r] = relu_f(x * sc + sh);
  }
}

// ---------------------------------------------------------------------------
// GEMM stage v2: OUT[r][n] = sum_k Ain[k][r] * W[k][n]
//  - lane owns CPL=2 consecutive columns (float2 W loads, 512B/wave contiguous)
//  - 8 broadcast float4 A-loads per k feed 64 FMAs (A is wave-uniform)
//  - 4 waves/block: same 128 cols, 4-way internal K-split, LDS-reduced
//  - KS blocks per column-group: partials combined via coalesced atomicAdd into
//    gacc (row-major [32][N]); counter-elected last block runs the epilogue,
//    where each thread owns one full output column (BN stats in registers).
//  epilogue modes: 0 +bias (fs, optional text term)  1 +bias->BN->relu
//                  2 +bias->sigmoid (row-major dst)  3 +bias+residual
// ---------------------------------------------------------------------------
__global__ void __launch_bounds__(BLK, 2) mm_stage2(
    const float* __restrict__ W, const float* __restrict__ Ain,
    const float* __restrict__ bias,
    const float* __restrict__ bng, const float* __restrict__ bnb,
    const float* __restrict__ res,
    const float* __restrict__ Wlow, const float* __restrict__ vvec,
    const int* __restrict__ flag,
    float* __restrict__ gacc, int* __restrict__ counter,
    float* __restrict__ dst,
    int K, int N, int KS, int mode)
{
  const int tid  = threadIdx.x;
  const int lane = tid & 63;
  const int wv   = tid >> 6;
  const int ncg  = N / COLS;
  const int colgroup = blockIdx.x % ncg;
  const int ks       = blockIdx.x / ncg;
  const int kchunk = K / (KS * KWAVES);
  const int k0     = (ks * KWAVES + wv) * kchunk;
  const int n0     = colgroup * COLS + lane * CPL;

  float2 acc[BS];
#pragma unroll
  for (int r = 0; r < BS; ++r) acc[r] = make_float2(0.f, 0.f);

  const float* wp = W + (size_t)k0 * N + n0;
  const float* ap = Ain + (size_t)k0 * BS;

#define ROWFMA(r, av) do { acc[r].x = fmaf((av), w.x, acc[r].x); \
                           acc[r].y = fmaf((av), w.y, acc[r].y); } while (0)

#pragma unroll 4
  for (int k = 0; k < kchunk; ++k) {
    float2 w = *(const float2*)(wp + (size_t)k * N);
    const float4* ar = (const float4*)(ap + (size_t)k * BS);
#pragma unroll
    for (int rq = 0; rq < 8; ++rq) {
      float4 a = ar[rq];
      ROWFMA(rq * 4 + 0, a.x);
      ROWFMA(rq * 4 + 1, a.y);
      ROWFMA(rq * 4 + 2, a.z);
      ROWFMA(rq * 4 + 3, a.w);
    }
  }
#undef ROWFMA

  // fs lower half: only if relu(fs_bn_b[E:]) has any nonzero (uniform branch,
  // zero for these inputs -> 64MB read skipped)
  if (Wlow != nullptr) {
    if (*flag) {
      float2 cp = make_float2(0.f, 0.f);
      const float* wl = Wlow + (size_t)k0 * N + n0;
      for (int k = 0; k < kchunk; ++k) {
        float vvk = vvec[k0 + k];
        float2 w = *(const float2*)(wl + (size_t)k * N);
        cp.x = fmaf(vvk, w.x, cp.x);
        cp.y = fmaf(vvk, w.y, cp.y);
      }
#pragma unroll
      for (int r = 0; r < BS; ++r) { acc[r].x += cp.x; acc[r].y += cp.y; }
    }
  }

  // cross-wave reduce (2 passes of 16 rows, 32KB LDS) + coalesced atomics
  __shared__ float sred[KWAVES][16][COLS];
  const int rc = tid & (COLS - 1);       // column within group for reduce
  const int rbase = (tid >> 7) * 8;      // 0 or 8
#pragma unroll
  for (int p = 0; p < 2; ++p) {
    if (p) __syncthreads();
#pragma unroll
    for (int r = 0; r < 16; ++r)
      *(float2*)&sred[wv][r][lane * CPL] = acc[p * 16 + r];
    __syncthreads();
#pragma unroll
    for (int i = 0; i < 8; ++i) {
      int r = rbase + i;
      float s = sred[0][r][rc] + sred[1][r][rc] + sred[2][r][rc] + sred[3][r][rc];
      atomicAdd(&gacc[(size_t)(p * 16 + r) * N + colgroup * COLS + rc], s);
    }
  }

  __threadfence();
  __shared__ int s_last;
  if (tid == 0) {
    int old = atomicAdd(counter + colgroup, 1);
    s_last = (old == KS - 1) ? 1 : 0;
  }
  __syncthreads();
  if (!s_last) return;

  // epilogue: threads 0..127 each own one full output column (32 rows in regs)
  if (tid < COLS) {
    const int n = colgroup * COLS + tid;
    float val[BS];
#pragma unroll
    for (int r = 0; r < BS; ++r)
      val[r] = __hip_atomic_load(&gacc[(size_t)r * N + n],
                                 __ATOMIC_RELAXED, __HIP_MEMORY_SCOPE_AGENT);
    const float bb = bias[n];
#pragma unroll
    for (int r = 0; r < BS; ++r) val[r] += bb;

    if (mode == 1) {
      float s = 0.f, s2 = 0.f;
#pragma unroll
      for (int r = 0; r < BS; ++r) { s += val[r]; s2 += val[r] * val[r]; }
      float mean = s * (1.f / BS);
      float var  = s2 * (1.f / BS) - mean * mean;
      float sc = bng[n] * rsqrtf(var + 1e-5f);
      float sh = bnb[n] - mean * sc;
      float* dp = dst + (size_t)n * BS;
#pragma unroll
      for (int r = 0; r < BS; ++r) dp[r] = relu_f(val[r] * sc + sh);
    } else if (mode == 2) {
#pragma unroll
      for (int r = 0; r < BS; ++r)
        dst[(size_t)r * EDIM + n] = 1.f / (1.f + __expf(-val[r]));
    } else if (mode == 3) {
      const float* rp = res + (size_t)n * BS;
      float* dp = dst + (size_t)n * BS;
#pragma unroll
      for (int r = 0; r < BS; ++r) dp[r] = val[r] + rp[r];
    } else {
      float* dp = dst + (size_t)n * BS;
#pragma unroll
      for (int r = 0; r < BS; ++r) dp[r] = val[r];
    }
  }
}

// ---------------------------------------------------------------------------
// final: out[j][r][e] = img[r][e]*g[r][e] + ff[r][e]*(1-g[r][e]); identical for
// all j -> compute once, write 8 j-copies per block (4 j-groups x 64 e-tiles).
// ---------------------------------------------------------------------------
__global__ void __launch_bounds__(BLK) final_kernel(
    const float* __restrict__ img, const float* __restrict__ grm,
    const float* __restrict__ fft, float* __restrict__ out)
{
  __shared__ float sff[BS][64];
  const int tid  = threadIdx.x;
  const int tile = blockIdx.x & 63;
  const int jg   = blockIdx.x >> 6;
  const int c  = tid >> 2;
  const int rb = (tid & 3) * 8;
  const float* src = fft + (size_t)(tile * 64 + c) * BS + rb;
#pragma unroll
  for (int u = 0; u < 8; ++u) sff[rb + u][c] = src[u];
  __syncthreads();

  const int le = tid & 63, rg = tid >> 6;
  const int e  = tile * 64 + le;
#pragma unroll
  for (int rr = 0; rr < 8; ++rr) {
    int r = rr * 4 + rg;
    float gv = grm[(size_t)r * EDIM + e];
    float iv = img[(size_t)r * EDIM + e];
    float o  = iv * gv + sff[r][le] * (1.f - gv);
#pragma unroll
    for (int jj = 0; jj < 8; ++jj) {
      int j = jg * 8 + jj;
      out[((size_t)(j * BS + r)) * EDIM + e] = o;
    }
  }
}

// ---------------------------------------------------------------------------
extern "C" void kernel_launch(void* const* d_in, const int* in_sizes, int n_in,
                              void* d_out, int out_size, void* d_ws, size_t ws_size,
                              hipStream_t stream)
{
  const float* img    = (const float*)d_in[0];
  // d_in[1] text_features: provably unused (BN over constant batch rows)
  const float* fs_bng = (const float*)d_in[2];
  const float* fs_bnb = (const float*)d_in[3];
  const float* fs_w   = (const float*)d_in[4];
  const float* fs_b   = (const float*)d_in[5];
  const float* gt_w1  = (const float*)d_in[6];
  const float* gt_b1  = (const float*)d_in[7];
  const float* gt_bng = (const float*)d_in[8];
  const float* gt_bnb = (const float*)d_in[9];
  const float* gt_w2  = (const float*)d_in[10];
  const float* gt_b2  = (const float*)d_in[11];
  const float* ee_w1  = (const float*)d_in[12];
  const float* ee_b1  = (const float*)d_in[13];
  const float* ee_bng = (const float*)d_in[14];
  const float* ee_bnb = (const float*)d_in[15];
  const float* ee_w2  = (const float*)d_in[16];
  const float* ee_b2  = (const float*)d_in[17];
  float* out = (float*)d_out;

  float* w = (float*)d_ws;
  size_t o = 0;
  float* acc_fs = w + o; o += (size_t)EDIM * BS;   // row-major [32][N]
  float* acc_g1 = w + o; o += (size_t)EDIM * BS;
  float* acc_g2 = w + o; o += (size_t)EDIM * BS;
  float* acc_ea[3]; for (int i = 0; i < 3; ++i) { acc_ea[i] = w + o; o += (size_t)(EDIM/2) * BS; }
  float* acc_eb[3]; for (int i = 0; i < 3; ++i) { acc_eb[i] = w + o; o += (size_t)EDIM * BS; }
  int* counters = (int*)(w + o); o += 1024;   // 9 stages x 64 + flag, zeroed
  int* flag = counters + 960;
  size_t zero_bytes = o * sizeof(float);
  float* act0 = w + o; o += (size_t)EDIM * BS;    // feature-major [E][32]
  float* vvec = w + o; o += EDIM;
  float* fbuf = w + o; o += (size_t)EDIM * BS;
  float* hgb  = w + o; o += (size_t)EDIM * BS;
  float* gbuf = w + o; o += (size_t)EDIM * BS;    // row-major [32][E]
  float* he[3];  for (int i = 0; i < 3; ++i) { he[i]  = w + o; o += (size_t)(EDIM/2) * BS; }
  float* ffb[3]; for (int i = 0; i < 3; ++i) { ffb[i] = w + o; o += (size_t)EDIM * BS; }

  hipMemsetAsync(d_ws, 0, zero_bytes, stream);

  prep_kernel<<<EDIM / BLK, BLK, 0, stream>>>(img, fs_bng, fs_bnb, act0, vvec, flag);

  const int KS_BIG = 16;   // N=4096: 32 colgroups * 16 = 512 blocks
  const int KS_EE1 = 32;   // N=2048: 16 colgroups * 32 = 512 blocks

  // fs: f = A0 @ fs_w[:E] + fs_b (+ optional text term via Wlow)
  mm_stage2<<<(EDIM / COLS) * KS_BIG, BLK, 0, stream>>>(
      fs_w, act0, fs_b, nullptr, nullptr, nullptr,
      fs_w + (size_t)EDIM * EDIM, vvec, flag,
      acc_fs, counters + 0, fbuf, EDIM, EDIM, KS_BIG, 0);

  // gating
  mm_stage2<<<(EDIM / COLS) * KS_BIG, BLK, 0, stream>>>(
      gt_w1, fbuf, gt_b1, gt_bng, gt_bnb, nullptr, nullptr, nullptr, nullptr,
      acc_g1, counters + 64, hgb, EDIM, EDIM, KS_BIG, 1);
  mm_stage2<<<(EDIM / COLS) * KS_BIG, BLK, 0, stream>>>(
      gt_w2, hgb, gt_b2, nullptr, nullptr, nullptr, nullptr, nullptr, nullptr,
      acc_g2, counters + 128, gbuf, EDIM, EDIM, KS_BIG, 2);

  // 3 error-encoding residual blocks
  const float* ffin = fbuf;
  for (int i = 0; i < 3; ++i) {
    mm_stage2<<<((EDIM / 2) / COLS) * KS_EE1, BLK, 0, stream>>>(
        ee_w1 + (size_t)i * EDIM * (EDIM / 2), ffin,
        ee_b1 + (size_t)i * (EDIM / 2), ee_bng + (size_t)i * (EDIM / 2),
        ee_bnb + (size_t)i * (EDIM / 2),
        nullptr, nullptr, nullptr, nullptr,
        acc_ea[i], counters + 192 + i * 128, he[i], EDIM, EDIM / 2, KS_EE1, 1);
    mm_stage2<<<(EDIM / COLS) * KS_BIG, BLK, 0, stream>>>(
        ee_w2 + (size_t)i * (EDIM / 2) * EDIM, he[i],
        ee_b2 + (size_t)i * EDIM, nullptr, nullptr, ffin,
        nullptr, nullptr, nullptr,
        acc_eb[i], counters + 256 + i * 128, ffb[i], EDIM / 2, EDIM, KS_BIG, 3);
    ffin = ffb[i];
  }

  final_kernel<<<64 * 4, BLK, 0, stream>>>(img, gbuf, ffin, out);
}